// Round 1
// baseline (71.032 us; speedup 1.0000x reference)
//
#include <hip/hip_runtime.h>
#include <math.h>

#define QN 8
#define NDIMS 2
#define LATENT 64
#define OUTC 32     // Q + Q + Q*NDIMS
#define IT 16       // i-rows per thread in pair kernel

// ---------------------------------------------------------------------------
// Phase 1: per-point feature MLP + derived quantities.
// For each point p: h = selu(W1 p + b1); a = softplus(W2 h + b2);
//   w = a[0:8], s = a[8:16], f = a[16:32] (pairs), phi[q] = f[q,0]p0 + f[q,1]p1
// Store per point (32 floats):
//   [0:8)   u[q]   = w*sqrt(s)*2^0.25     (so uA*uB = wA*wB*sqrt(2 sA sB))
//   [8:16)  ssq[q] = s*s
//   [16:24) cos(2*pi*phi[q])
//   [24:32) sin(2*pi*phi[q])
// ---------------------------------------------------------------------------
__global__ __launch_bounds__(256) void feat_kernel(
    const float* __restrict__ x, const float* __restrict__ y, int n,
    const float* __restrict__ W1, const float* __restrict__ b1,
    const float* __restrict__ W2, const float* __restrict__ b2,
    float* __restrict__ featX, float* __restrict__ featY)
{
    int t = blockIdx.x * blockDim.x + threadIdx.x;
    if (t >= 2 * n) return;
    const float* p   = (t < n) ? (x + 2 * t)      : (y + 2 * (t - n));
    float*       fo  = (t < n) ? (featX + 32 * t) : (featY + 32 * (t - n));
    float p0 = p[0], p1 = p[1];

    const float kScale = 1.0507009873554804934193349852946f;
    const float kAlpha = 1.6732632423543772848170429916717f;

    float h[LATENT];
    #pragma unroll
    for (int k = 0; k < LATENT; ++k) {
        float z = fmaf(W1[2 * k], p0, fmaf(W1[2 * k + 1], p1, b1[k]));
        h[k] = kScale * (z > 0.f ? z : kAlpha * expm1f(z));
    }

    float a[OUTC];
    #pragma unroll
    for (int o = 0; o < OUTC; ++o) {      // fully unrolled -> static indices, no scratch
        float z = b2[o];
        #pragma unroll
        for (int k = 0; k < LATENT; ++k)
            z = fmaf(W2[o * LATENT + k], h[k], z);
        // numerically stable softplus = max(z,0) + log1p(exp(-|z|))
        a[o] = fmaxf(z, 0.f) + log1pf(expf(-fabsf(z)));
    }

    const float TWO_PI  = 6.283185307179586f;
    const float ROOT4_2 = 1.18920711500272107f;   // 2^(1/4)
    #pragma unroll
    for (int q = 0; q < QN; ++q) {
        float w  = a[q];
        float s  = a[QN + q];
        float f0 = a[2 * QN + 2 * q];
        float f1 = a[2 * QN + 2 * q + 1];
        float phi = fmaf(f0, p0, f1 * p1);
        float sn, cs;
        sincosf(TWO_PI * phi, &sn, &cs);
        fo[q]          = w * sqrtf(s) * ROOT4_2;
        fo[QN + q]     = s * s;
        fo[2 * QN + q] = cs;
        fo[3 * QN + q] = sn;
    }
}

// ---------------------------------------------------------------------------
// Phase 2: pairwise kernel.
// out[i,j] = sum_q uA*uB/s2 * exp(-d2/s2) * (cA*cB + snA*snB),  s2 = ssqA+ssqB
// Thread -> one j (coalesced output), loops IT consecutive i's whose features
// are wave-uniform (scalar loads). B-side features held in registers.
// ---------------------------------------------------------------------------
__global__ __launch_bounds__(256) void pair_kernel(
    const float* __restrict__ x, const float* __restrict__ y, int n,
    const float* __restrict__ fA, const float* __restrict__ fB,
    float* __restrict__ out)
{
    int j = blockIdx.x * 256 + threadIdx.x;
    if (j >= n) return;
    int i0 = blockIdx.y * IT;

    float uB[QN], ssB[QN], cB[QN], snB[QN];
    const float* fb = fB + 32 * j;
    #pragma unroll
    for (int q = 0; q < QN; ++q) {
        uB[q]  = fb[q];
        ssB[q] = fb[QN + q];
        cB[q]  = fb[2 * QN + q];
        snB[q] = fb[3 * QN + q];
    }
    float y0 = y[2 * j], y1 = y[2 * j + 1];

    #pragma unroll 4
    for (int ii = 0; ii < IT; ++ii) {
        int i = i0 + ii;
        if (i >= n) break;
        const float* fa = fA + 32 * i;           // wave-uniform -> s_load
        float dx = x[2 * i]     - y0;
        float dy = x[2 * i + 1] - y1;
        float d2 = fmaf(dx, dx, dy * dy);
        float acc = 0.f;
        #pragma unroll
        for (int q = 0; q < QN; ++q) {
            float s2  = fa[QN + q] + ssB[q];
            float inv = __builtin_amdgcn_rcpf(s2);
            float e   = __expf(-d2 * inv);
            float g   = fa[q] * uB[q] * inv * e;
            float c   = fmaf(fa[2 * QN + q], cB[q], fa[3 * QN + q] * snB[q]);
            acc = fmaf(g, c, acc);
        }
        out[(long)i * n + j] = acc;
    }
}

extern "C" void kernel_launch(void* const* d_in, const int* in_sizes, int n_in,
                              void* d_out, int out_size, void* d_ws, size_t ws_size,
                              hipStream_t stream)
{
    const float* x  = (const float*)d_in[0];
    const float* y  = (const float*)d_in[1];
    const float* W1 = (const float*)d_in[2];
    const float* b1 = (const float*)d_in[3];
    const float* W2 = (const float*)d_in[4];
    const float* b2 = (const float*)d_in[5];
    float* out = (float*)d_out;

    int n = in_sizes[0] / NDIMS;     // 2048

    float* featX = (float*)d_ws;
    float* featY = featX + (size_t)n * 32;

    int featThreads = 2 * n;
    hipLaunchKernelGGL(feat_kernel, dim3((featThreads + 255) / 256), dim3(256), 0, stream,
                       x, y, n, W1, b1, W2, b2, featX, featY);

    dim3 grid((n + 255) / 256, (n + IT - 1) / IT);
    hipLaunchKernelGGL(pair_kernel, grid, dim3(256), 0, stream,
                       x, y, n, featX, featY, out);
}

// Round 2
// 33.604 us; speedup vs baseline: 2.1138x; 2.1138x over previous
//
#include <hip/hip_runtime.h>
#include <math.h>

#define QN 8
#define NDIMS 2
#define LATENT 64
#define OUTC 32     // Q + Q + Q*NDIMS
#define IT 16       // i-rows per thread in pair kernel
#define PPB 4       // points per block in feat kernel

// ---------------------------------------------------------------------------
// Phase 1: per-point feature MLP + derived quantities.
// One 64-lane group per point; 4 points per 256-thread block.
// Store per point (32 floats):
//   [0:8)   u[q]   = w*sqrt(s)*2^0.25     (so uA*uB = wA*wB*sqrt(2 sA sB))
//   [8:16)  ssq[q] = s*s
//   [16:24) cos(2*pi*phi[q])
//   [24:32) sin(2*pi*phi[q])
// ---------------------------------------------------------------------------
__global__ __launch_bounds__(256) void feat_kernel(
    const float* __restrict__ x, const float* __restrict__ y, int n,
    const float* __restrict__ W1, const float* __restrict__ b1,
    const float* __restrict__ W2, const float* __restrict__ b2,
    float* __restrict__ featX, float* __restrict__ featY)
{
    __shared__ float h_lds[PPB][LATENT];
    __shared__ float a_lds[PPB][OUTC];
    __shared__ float p_lds[PPB][2];

    const int t    = threadIdx.x;
    const int npts = 2 * n;

    const float kScale = 1.0507009873554804934193349852946f;
    const float kAlpha = 1.6732632423543772848170429916717f;

    // ---- Stage A: h[k] = selu(W1 p + b1), one lane per latent unit ----
    {
        int pt = t >> 6, k = t & 63;
        int gp = blockIdx.x * PPB + pt;
        if (gp < npts) {
            const float* p = (gp < n) ? (x + 2 * gp) : (y + 2 * (gp - n));
            float p0 = p[0], p1 = p[1];
            if (k == 0) { p_lds[pt][0] = p0; p_lds[pt][1] = p1; }
            float z  = fmaf(W1[2 * k], p0, fmaf(W1[2 * k + 1], p1, b1[k]));
            float hk = kScale * (z > 0.f ? z : kAlpha * (__expf(z) - 1.f));
            h_lds[pt][k] = hk;
        }
    }
    __syncthreads();

    // ---- Stage B: a[o] = softplus(W2[o,:] . h + b2[o]), 32 lanes/point ----
    if (t < PPB * OUTC) {
        int pt = t >> 5, o = t & 31;
        int gp = blockIdx.x * PPB + pt;
        if (gp < npts) {
            const float4* w2 = (const float4*)(W2 + (size_t)o * LATENT);
            const float4* hv = (const float4*)(&h_lds[pt][0]);
            float z0 = b2[o], z1 = 0.f, z2 = 0.f, z3 = 0.f;
            #pragma unroll
            for (int c = 0; c < LATENT / 16; ++c) {   // 4 chunks of 4xfloat4
                float4 w0 = w2[4 * c + 0], h0 = hv[4 * c + 0];
                float4 w1v = w2[4 * c + 1], h1 = hv[4 * c + 1];
                float4 w2v = w2[4 * c + 2], h2 = hv[4 * c + 2];
                float4 w3 = w2[4 * c + 3], h3 = hv[4 * c + 3];
                z0 = fmaf(w0.x, h0.x, fmaf(w0.y, h0.y, fmaf(w0.z, h0.z, fmaf(w0.w, h0.w, z0))));
                z1 = fmaf(w1v.x, h1.x, fmaf(w1v.y, h1.y, fmaf(w1v.z, h1.z, fmaf(w1v.w, h1.w, z1))));
                z2 = fmaf(w2v.x, h2.x, fmaf(w2v.y, h2.y, fmaf(w2v.z, h2.z, fmaf(w2v.w, h2.w, z2))));
                z3 = fmaf(w3.x, h3.x, fmaf(w3.y, h3.y, fmaf(w3.z, h3.z, fmaf(w3.w, h3.w, z3))));
            }
            float z = (z0 + z1) + (z2 + z3);
            // stable softplus: max(z,0) + log(1 + exp(-|z|))
            float e = __expf(-fabsf(z));
            a_lds[pt][o] = fmaxf(z, 0.f) + __logf(1.f + e);
        }
    }
    __syncthreads();

    // ---- Stage C: derived per-q features, 8 lanes/point ----
    if (t < PPB * QN) {
        int pt = t >> 3, q = t & 7;
        int gp = blockIdx.x * PPB + pt;
        if (gp < npts) {
            float w  = a_lds[pt][q];
            float s  = a_lds[pt][QN + q];
            float f0 = a_lds[pt][2 * QN + 2 * q];
            float f1 = a_lds[pt][2 * QN + 2 * q + 1];
            float p0 = p_lds[pt][0], p1 = p_lds[pt][1];
            float phi = fmaf(f0, p0, f1 * p1);
            // sin/cos of 2*pi*phi; reduce to [0,1) revolutions first
            float r   = phi - floorf(phi);
            float ang = 6.283185307179586f * r;
            float cs  = __cosf(ang);
            float sn  = __sinf(ang);
            const float ROOT4_2 = 1.18920711500272107f;   // 2^(1/4)
            float* fo = (gp < n) ? (featX + 32 * gp) : (featY + 32 * (gp - n));
            fo[q]          = w * sqrtf(s) * ROOT4_2;
            fo[QN + q]     = s * s;
            fo[2 * QN + q] = cs;
            fo[3 * QN + q] = sn;
        }
    }
}

// ---------------------------------------------------------------------------
// Phase 2: pairwise kernel (unchanged — already at ~88% of write BW ceiling).
// out[i,j] = sum_q uA*uB/s2 * exp(-d2/s2) * (cA*cB + snA*snB),  s2 = ssqA+ssqB
// ---------------------------------------------------------------------------
__global__ __launch_bounds__(256) void pair_kernel(
    const float* __restrict__ x, const float* __restrict__ y, int n,
    const float* __restrict__ fA, const float* __restrict__ fB,
    float* __restrict__ out)
{
    int j = blockIdx.x * 256 + threadIdx.x;
    if (j >= n) return;
    int i0 = blockIdx.y * IT;

    float uB[QN], ssB[QN], cB[QN], snB[QN];
    const float* fb = fB + 32 * j;
    #pragma unroll
    for (int q = 0; q < QN; ++q) {
        uB[q]  = fb[q];
        ssB[q] = fb[QN + q];
        cB[q]  = fb[2 * QN + q];
        snB[q] = fb[3 * QN + q];
    }
    float y0 = y[2 * j], y1 = y[2 * j + 1];

    #pragma unroll 4
    for (int ii = 0; ii < IT; ++ii) {
        int i = i0 + ii;
        if (i >= n) break;
        const float* fa = fA + 32 * i;           // wave-uniform -> s_load
        float dx = x[2 * i]     - y0;
        float dy = x[2 * i + 1] - y1;
        float d2 = fmaf(dx, dx, dy * dy);
        float acc = 0.f;
        #pragma unroll
        for (int q = 0; q < QN; ++q) {
            float s2  = fa[QN + q] + ssB[q];
            float inv = __builtin_amdgcn_rcpf(s2);
            float e   = __expf(-d2 * inv);
            float g   = fa[q] * uB[q] * inv * e;
            float c   = fmaf(fa[2 * QN + q], cB[q], fa[3 * QN + q] * snB[q]);
            acc = fmaf(g, c, acc);
        }
        out[(long)i * n + j] = acc;
    }
}

extern "C" void kernel_launch(void* const* d_in, const int* in_sizes, int n_in,
                              void* d_out, int out_size, void* d_ws, size_t ws_size,
                              hipStream_t stream)
{
    const float* x  = (const float*)d_in[0];
    const float* y  = (const float*)d_in[1];
    const float* W1 = (const float*)d_in[2];
    const float* b1 = (const float*)d_in[3];
    const float* W2 = (const float*)d_in[4];
    const float* b2 = (const float*)d_in[5];
    float* out = (float*)d_out;

    int n = in_sizes[0] / NDIMS;     // 2048

    float* featX = (float*)d_ws;
    float* featY = featX + (size_t)n * 32;

    int npts = 2 * n;
    hipLaunchKernelGGL(feat_kernel, dim3((npts + PPB - 1) / PPB), dim3(256), 0, stream,
                       x, y, n, W1, b1, W2, b2, featX, featY);

    dim3 grid((n + 255) / 256, (n + IT - 1) / IT);
    hipLaunchKernelGGL(pair_kernel, grid, dim3(256), 0, stream,
                       x, y, n, featX, featY, out);
}